// Round 3
// baseline (328.167 us; speedup 1.0000x reference)
//
#include <hip/hip_runtime.h>

#define Bdim 8
#define Tdim 100
#define Sdim 400
#define Kk   8
#define Hdim 512
#define Vdim 32000
#define Mdim 800          // B*T
#define VHALF 16000

typedef __attribute__((ext_vector_type(8))) short short8;     // 8 bf16 = 4 VGPRs
typedef __attribute__((ext_vector_type(4))) short short4v;    // 4 bf16 = 2 VGPRs
typedef __attribute__((ext_vector_type(4))) float float4_t;   // MFMA acc

static __device__ __forceinline__ unsigned short f2bf(float f) {
    unsigned int x = __float_as_uint(f);
    return (unsigned short)((x + 0x7fffu + ((x >> 16) & 1u)) >> 16);   // RNE
}
static __device__ __forceinline__ float bf2f(unsigned short h) {
    return __uint_as_float(((unsigned int)h) << 16);
}

// async 16B global->LDS (wave-uniform LDS base + lane*16)
static __device__ __forceinline__ void gload_lds16(const void* g, void* s) {
    __builtin_amdgcn_global_load_lds((const __attribute__((address_space(1))) void*)g,
                                     (__attribute__((address_space(3))) void*)s, 16, 0, 0);
}

// ---------------- prep: dec_out fp32 -> bf16 (vectorized x4); also zeros rowsum ----------------
__global__ void convert_a_kernel(const float* __restrict__ A, unsigned short* __restrict__ Abf,
                                 float* __restrict__ rowsum, int n4) {
    int i = blockIdx.x * blockDim.x + threadIdx.x;
    if (i < Mdim) rowsum[i] = 0.f;
    if (i < n4) {
        float4 f = ((const float4*)A)[i];
        short4v s;
        s[0] = (short)f2bf(f.x); s[1] = (short)f2bf(f.y);
        s[2] = (short)f2bf(f.z); s[3] = (short)f2bf(f.w);
        *(short4v*)(Abf + i * 4) = s;
    }
}

// ---------------- prep: W (512 x 32000) fp32 -> WT (32000 x 512) bf16 ----------------
// 64x64 tile, float4 loads (16B/lane), short8 stores (16B/lane). 65-pad LDS.
__global__ __launch_bounds__(256) void transpose_kernel(const float* __restrict__ W,
                                                        unsigned short* __restrict__ WT) {
    __shared__ float tile[64][65];
    const int k0 = blockIdx.y * 64;
    const int v0 = blockIdx.x * 64;
    const int t  = threadIdx.x;
    const int tx = t & 15;            // float4 col within tile row
    const int ty = t >> 4;            // 0..15
#pragma unroll
    for (int i = 0; i < 64; i += 16) {
        float4 f = *(const float4*)&W[(size_t)(k0 + ty + i) * Vdim + v0 + tx * 4];
        tile[ty + i][tx * 4 + 0] = f.x;
        tile[ty + i][tx * 4 + 1] = f.y;
        tile[ty + i][tx * 4 + 2] = f.z;
        tile[ty + i][tx * 4 + 3] = f.w;
    }
    __syncthreads();
    const int c = t & 7;              // k-chunk of 8
    const int v = t >> 3;             // 0..31
#pragma unroll
    for (int i = 0; i < 64; i += 32) {
        short8 s;
#pragma unroll
        for (int j = 0; j < 8; ++j) s[j] = (short)f2bf(tile[c * 8 + j][v + i]);
        *(short8*)&WT[(size_t)(v0 + v + i) * Hdim + k0 + c * 8] = s;
    }
}

// ---------------- GEMM: logits(800x32000) = Abf * WT^T + bias; bf16 store + row sumexp ----
// Round-3 restructure for TLP (latency-bound diagnosis: MfmaUtil 15%, occ 17%, HBM 13%):
//   64x64 tile, 4 waves (2x2 of 32x32), BK=64 double-buffered => 32 KB LDS, 16 AGPR acc.
//   5 blocks/CU by LDS (was 2), grid 13x500=6500 (~25 slots/CU) so other blocks' compute
//   covers each block's barrier-drain stall. XCD swizzle bijective for nwg=6500, m-fastest.
__global__ __launch_bounds__(256) void gemm_kernel(const unsigned short* __restrict__ Abf,
                                                   const unsigned short* __restrict__ WT,
                                                   const float* __restrict__ bias,
                                                   unsigned short* __restrict__ logitsbf,
                                                   float* __restrict__ rowsum) {
    __shared__ __align__(16) unsigned short As[2 * 64 * 64];   // 2 x 8 KB
    __shared__ __align__(16) unsigned short Bs[2 * 64 * 64];   // 2 x 8 KB

    const int tid  = threadIdx.x;
    const int lane = tid & 63;
    const int wave = tid >> 6;
    const int l15  = lane & 15;
    const int kq   = lane >> 4;            // 0..3

    // bijective XCD swizzle (m204): nwg = 13*500 = 6500
    const int NWG = 13 * 500;
    const int orig = blockIdx.x;
    const int xcd = orig & 7;
    const int q8  = NWG >> 3;              // 812
    const int r8  = NWG & 7;               // 4
    const int wg  = (xcd < r8 ? xcd * (q8 + 1) : r8 * (q8 + 1) + (xcd - r8) * q8) + (orig >> 3);
    const int m_blk = (wg % 13) * 64;      // m-fastest: B-tile reuse is L2-local
    const int n_blk = (wg / 13) * 64;

    const int wm = wave & 1, wn = wave >> 1;
    const int m0 = wm * 32, n0 = wn * 32;

    // staging: 512 16B-chunks per matrix; chunk = (q*4+wave)*64 + lane, q=0..1
    const unsigned short* agp[2];
    const unsigned short* bgp[2];
    int lslot[2];
#pragma unroll
    for (int q = 0; q < 2; ++q) {
        int chunk = (q * 4 + wave) * 64 + lane;
        int row = chunk >> 3, c = chunk & 7;
        int gc  = c ^ (row & 7);                 // XOR swizzle: lane fetches the chunk that
        int arow = m_blk + row;                  // belongs at its contiguous LDS slot
        if (arow >= Mdim) arow = Mdim - 1;       // clamp; epilogue masks
        agp[q] = Abf + (size_t)arow * Hdim + gc * 8;
        bgp[q] = WT + (size_t)(n_blk + row) * Hdim + gc * 8;
        lslot[q] = (q * 4 + wave) * 512;         // wave-uniform base (shorts)
    }

    // fragment LDS offsets (shorts): row*64 + ((ks*4+kq)^(row&7))*8
    int a_off[2][2], b_off[2][2];
#pragma unroll
    for (int ks = 0; ks < 2; ++ks)
#pragma unroll
        for (int i = 0; i < 2; ++i) {
            int ra = m0 + i * 16 + l15;
            a_off[ks][i] = ra * 64 + (((ks * 4 + kq) ^ (ra & 7)) * 8);
            int rb = n0 + i * 16 + l15;
            b_off[ks][i] = rb * 64 + (((ks * 4 + kq) ^ (rb & 7)) * 8);
        }

    float4_t acc[2][2] = {};

    // prologue: stage K-tile 0 into buffer 0
#pragma unroll
    for (int q = 0; q < 2; ++q) {
        gload_lds16(agp[q], As + lslot[q]);
        gload_lds16(bgp[q], Bs + lslot[q]);
    }
    __syncthreads();

    int cur = 0;
#pragma unroll
    for (int kt = 0; kt < 8; ++kt) {
        // prefetch next K-tile into the other buffer (in flight during compute)
        if (kt < 7) {
            const int ko = (kt + 1) * 64;
            const int nb = (cur ^ 1) * 4096;
#pragma unroll
            for (int q = 0; q < 2; ++q) {
                gload_lds16(agp[q] + ko, As + nb + lslot[q]);
                gload_lds16(bgp[q] + ko, Bs + nb + lslot[q]);
            }
        }
        const unsigned short* Ab = As + cur * 4096;
        const unsigned short* Bb = Bs + cur * 4096;
#pragma unroll
        for (int ks = 0; ks < 2; ++ks) {
            short8 af[2], bfr[2];
#pragma unroll
            for (int i = 0; i < 2; ++i) af[i]  = *(const short8*)(Ab + a_off[ks][i]);
#pragma unroll
            for (int j = 0; j < 2; ++j) bfr[j] = *(const short8*)(Bb + b_off[ks][j]);
#pragma unroll
            for (int i = 0; i < 2; ++i)
#pragma unroll
                for (int j = 0; j < 2; ++j)
                    acc[i][j] = __builtin_amdgcn_mfma_f32_16x16x32_bf16(af[i], bfr[j], acc[i][j], 0, 0, 0);
        }
        if (kt < 7) {
            __syncthreads();     // drains prefetch (vmcnt 0) + lgkm; buffers safe to swap
            cur ^= 1;
        }
    }

    // epilogue: bias add, bf16 store, per-row partial sum of exp -> atomicAdd rowsum
    float bj[2];
#pragma unroll
    for (int j = 0; j < 2; ++j) bj[j] = bias[n_blk + n0 + j * 16 + l15];

#pragma unroll
    for (int i = 0; i < 2; ++i) {
        float se[4] = {0.f, 0.f, 0.f, 0.f};
        int grow0 = m_blk + m0 + i * 16 + kq * 4;      // + r
#pragma unroll
        for (int j = 0; j < 2; ++j) {
            int col = n_blk + n0 + j * 16 + l15;
#pragma unroll
            for (int r = 0; r < 4; ++r) {
                float v = acc[i][j][r] + bj[j];
                se[r] += __expf(v);
                if (grow0 + r < Mdim)
                    logitsbf[(size_t)(grow0 + r) * Vdim + col] = f2bf(v);
            }
        }
#pragma unroll
        for (int r = 0; r < 4; ++r) {
#pragma unroll
            for (int off = 8; off; off >>= 1)
                se[r] += __shfl_xor(se[r], off, 64);   // reduce over the 16 cols (l15)
        }
        if (l15 == 0) {
#pragma unroll
            for (int r = 0; r < 4; ++r)
                if (grow0 + r < Mdim) atomicAdd(&rowsum[grow0 + r], se[r]);
        }
    }
}

// ---------------- combine: sparse copy-dist scatter + log blend (single logits pass) ----
__global__ __launch_bounds__(512) void combine_kernel(const unsigned short* __restrict__ logitsbf,
                                                      const float* __restrict__ weights,
                                                      const float* __restrict__ p_trans,
                                                      const float* __restrict__ trans_probs,
                                                      const float* __restrict__ probs,
                                                      const int* __restrict__ idxes,
                                                      const float* __restrict__ rowsum,
                                                      float* __restrict__ out) {
    __shared__ __align__(16) float ts[VHALF];

    int bt = blockIdx.x;           // 0..799
    int b  = bt / Tdim;
    int tid = threadIdx.x;

    float pt = p_trans[bt];
    float c1 = (1.f - pt) / rowsum[bt];

    const short8* lrow8 = (const short8*)(logitsbf + (size_t)bt * Vdim);
    float4* out4 = (float4*)(out + (size_t)bt * Vdim);
    float4* ts4  = (float4*)ts;

    for (int h = 0; h < 2; ++h) {
        float4 z = make_float4(0.f, 0.f, 0.f, 0.f);
        for (int i = tid; i < VHALF / 4; i += 512) ts4[i] = z;
        __syncthreads();

        for (int i = tid; i < Sdim * Kk; i += 512) {
            float pv  = probs[b * (Sdim * Kk) + i];
            float tpv = trans_probs[b * (Sdim * Kk) + i];
            int   idx = idxes[b * (Sdim * Kk) + i];
            int   rel = idx - h * VHALF;
            if (pv > 0.05f && (unsigned)rel < (unsigned)VHALF) {
                float w = weights[bt * Sdim + (i >> 3)];
                atomicAdd(&ts[rel], w * tpv);
            }
        }
        __syncthreads();

        for (int i = tid; i < VHALF / 8; i += 512) {
            short8 x8 = lrow8[h * (VHALF / 8) + i];
            float4 t0 = ts4[i * 2];
            float4 t1 = ts4[i * 2 + 1];
            float4 o0, o1;
            o0.x = __logf(pt * t0.x + c1 * __expf(bf2f((unsigned short)x8[0])));
            o0.y = __logf(pt * t0.y + c1 * __expf(bf2f((unsigned short)x8[1])));
            o0.z = __logf(pt * t0.z + c1 * __expf(bf2f((unsigned short)x8[2])));
            o0.w = __logf(pt * t0.w + c1 * __expf(bf2f((unsigned short)x8[3])));
            o1.x = __logf(pt * t1.x + c1 * __expf(bf2f((unsigned short)x8[4])));
            o1.y = __logf(pt * t1.y + c1 * __expf(bf2f((unsigned short)x8[5])));
            o1.z = __logf(pt * t1.z + c1 * __expf(bf2f((unsigned short)x8[6])));
            o1.w = __logf(pt * t1.w + c1 * __expf(bf2f((unsigned short)x8[7])));
            out4[(h * (VHALF / 8) + i) * 2]     = o0;
            out4[(h * (VHALF / 8) + i) * 2 + 1] = o1;
        }
        __syncthreads();
    }
}

extern "C" void kernel_launch(void* const* d_in, const int* in_sizes, int n_in,
                              void* d_out, int out_size, void* d_ws, size_t ws_size,
                              hipStream_t stream) {
    const float* dec_out     = (const float*)d_in[0];   // (8,100,512)
    const float* W           = (const float*)d_in[1];   // (512,32000)
    const float* bias        = (const float*)d_in[2];   // (32000,)
    const float* weights     = (const float*)d_in[3];   // (8,100,400)
    const float* p_trans     = (const float*)d_in[4];   // (8,100,1)
    const float* trans_probs = (const float*)d_in[5];   // (8,400,8)
    const float* probs       = (const float*)d_in[6];   // (8,400,8)
    const int*   idxes       = (const int*)d_in[7];     // (8,400,8)
    float* out = (float*)d_out;

    char* wsb = (char*)d_ws;
    unsigned short* Abf      = (unsigned short*)wsb;                      // 819,200 B
    unsigned short* WT       = (unsigned short*)(wsb + (1ull << 20));     // 32.8 MB
    unsigned short* logitsbf = (unsigned short*)(wsb + (35ull << 20));    // 51.2 MB
    float*          rowsum   = (float*)(wsb + (90ull << 20));             // 3200 B

    convert_a_kernel<<<dim3((Mdim * Hdim / 4 + 255) / 256), dim3(256), 0, stream>>>(dec_out, Abf, rowsum, Mdim * Hdim / 4);
    transpose_kernel<<<dim3(Vdim / 64, Hdim / 64), dim3(256), 0, stream>>>(W, WT);
    gemm_kernel<<<dim3(13 * 500), dim3(256), 0, stream>>>(Abf, WT, bias, logitsbf, rowsum);
    combine_kernel<<<dim3(Mdim), dim3(512), 0, stream>>>(logitsbf, weights, p_trans, trans_probs,
                                                         probs, idxes, rowsum, out);
}

// Round 4
// 302.372 us; speedup vs baseline: 1.0853x; 1.0853x over previous
//
#include <hip/hip_runtime.h>

#define Bdim 8
#define Tdim 100
#define Sdim 400
#define Kk   8
#define Hdim 512
#define Vdim 32000
#define Mdim 800          // B*T
#define VHALF 16000

typedef __attribute__((ext_vector_type(8))) short short8;     // 8 bf16 = 4 VGPRs
typedef __attribute__((ext_vector_type(4))) short short4v;    // 4 bf16 = 2 VGPRs
typedef __attribute__((ext_vector_type(4))) float float4_t;   // MFMA acc

static __device__ __forceinline__ unsigned short f2bf(float f) {
    unsigned int x = __float_as_uint(f);
    return (unsigned short)((x + 0x7fffu + ((x >> 16) & 1u)) >> 16);   // RNE
}
static __device__ __forceinline__ float bf2f(unsigned short h) {
    return __uint_as_float(((unsigned int)h) << 16);
}

// async 16B global->LDS (wave-uniform LDS base + lane*16)
static __device__ __forceinline__ void gload_lds16(const void* g, void* s) {
    __builtin_amdgcn_global_load_lds((const __attribute__((address_space(1))) void*)g,
                                     (__attribute__((address_space(3))) void*)s, 16, 0, 0);
}

// ---------------- prep: dec_out fp32 -> bf16 (vectorized x4); also zeros rowsum ----------------
__global__ void convert_a_kernel(const float* __restrict__ A, unsigned short* __restrict__ Abf,
                                 float* __restrict__ rowsum, int n4) {
    int i = blockIdx.x * blockDim.x + threadIdx.x;
    if (i < Mdim) rowsum[i] = 0.f;
    if (i < n4) {
        float4 f = ((const float4*)A)[i];
        short4v s;
        s[0] = (short)f2bf(f.x); s[1] = (short)f2bf(f.y);
        s[2] = (short)f2bf(f.z); s[3] = (short)f2bf(f.w);
        *(short4v*)(Abf + i * 4) = s;
    }
}

// ---------------- prep: W (512 x 32000) fp32 -> WT (32000 x 512) bf16 ----------------
__global__ __launch_bounds__(256) void transpose_kernel(const float* __restrict__ W,
                                                        unsigned short* __restrict__ WT) {
    __shared__ float tile[64][65];
    const int k0 = blockIdx.y * 64;
    const int v0 = blockIdx.x * 64;
    const int t  = threadIdx.x;
    const int tx = t & 15;            // float4 col within tile row
    const int ty = t >> 4;            // 0..15
#pragma unroll
    for (int i = 0; i < 64; i += 16) {
        float4 f = *(const float4*)&W[(size_t)(k0 + ty + i) * Vdim + v0 + tx * 4];
        tile[ty + i][tx * 4 + 0] = f.x;
        tile[ty + i][tx * 4 + 1] = f.y;
        tile[ty + i][tx * 4 + 2] = f.z;
        tile[ty + i][tx * 4 + 3] = f.w;
    }
    __syncthreads();
    const int c = t & 7;              // k-chunk of 8
    const int v = t >> 3;             // 0..31
#pragma unroll
    for (int i = 0; i < 64; i += 32) {
        short8 s;
#pragma unroll
        for (int j = 0; j < 8; ++j) s[j] = (short)f2bf(tile[c * 8 + j][v + i]);
        *(short8*)&WT[(size_t)(v0 + v + i) * Hdim + k0 + c * 8] = s;
    }
}

// ---------------- GEMM: logits(800x32000) = Abf * WT^T + bias; bf16 store + row sumexp ----
// Round-4: amortization restructure (R3 lesson: smaller tiles/more TLP made it WORSE).
//   256x256 tile, 8 waves (2Mx4N, 128x64 out each), BK=64 dbuf => 128 KB LDS, 1 block/CU.
//   4x fewer epilogues; 64 MFMA/wave per K-step per barrier (was 16).
//   Single barrier per K-step, counted-stale vmcnt: wait vmcnt(0) on loads issued a full
//   compute-phase earlier (near-free), barrier publishes + gates overwrite, THEN issue
//   next stage so it flies during compute. No fresh-drain stall anywhere in the loop.
__global__ __launch_bounds__(512, 2) void gemm_kernel(const unsigned short* __restrict__ Abf,
                                                      const unsigned short* __restrict__ WT,
                                                      const float* __restrict__ bias,
                                                      unsigned short* __restrict__ logitsbf,
                                                      float* __restrict__ rowsum) {
    __shared__ __align__(16) unsigned short As[2 * 256 * 64];   // 2 x 32 KB
    __shared__ __align__(16) unsigned short Bs[2 * 256 * 64];   // 2 x 32 KB

    const int tid  = threadIdx.x;
    const int lane = tid & 63;
    const int wave = tid >> 6;             // 0..7
    const int l15  = lane & 15;
    const int kq   = lane >> 4;            // 0..3

    // bijective XCD swizzle (m204): nwg = 4*125 = 500
    const int NWG = 500;
    const int orig = blockIdx.x;
    const int xcd = orig & 7;
    const int q8  = NWG >> 3;              // 62
    const int r8  = NWG & 7;               // 4
    const int wg  = (xcd < r8 ? xcd * (q8 + 1) : r8 * (q8 + 1) + (xcd - r8) * q8) + (orig >> 3);
    const int m_blk = (wg & 3) * 256;      // m-fastest: B-panel reuse is L2-local
    const int n_blk = (wg >> 2) * 256;

    const int wm = wave & 1, wn = wave >> 1;   // 2M x 4N waves
    const int m0 = wm * 128, n0 = wn * 64;     // per-wave 128x64 output

    // staging: 2048 16B-chunks per matrix; chunk = (q*8+wave)*64 + lane, q=0..3
    const unsigned short* agp[4];
    const unsigned short* bgp[4];
    int lslot[4];
#pragma unroll
    for (int q = 0; q < 4; ++q) {
        int chunk = (q * 8 + wave) * 64 + lane;
        int row = chunk >> 3, c = chunk & 7;
        int gc  = c ^ (row & 7);                 // XOR swizzle: lane fetches the chunk that
        int arow = m_blk + row;                  // belongs at its contiguous LDS slot
        if (arow >= Mdim) arow = Mdim - 1;       // clamp; epilogue masks
        agp[q] = Abf + (size_t)arow * Hdim + gc * 8;
        bgp[q] = WT + (size_t)(n_blk + row) * Hdim + gc * 8;
        lslot[q] = (q * 8 + wave) * 512;         // wave-uniform base (shorts)
    }

    // fragment LDS offsets (shorts): row*64 + ((ks*4+kq)^(row&7))*8
    int a_off[2][8], b_off[2][4];
#pragma unroll
    for (int ks = 0; ks < 2; ++ks) {
#pragma unroll
        for (int i = 0; i < 8; ++i) {
            int ra = m0 + i * 16 + l15;
            a_off[ks][i] = ra * 64 + (((ks * 4 + kq) ^ (ra & 7)) * 8);
        }
#pragma unroll
        for (int j = 0; j < 4; ++j) {
            int rb = n0 + j * 16 + l15;
            b_off[ks][j] = rb * 64 + (((ks * 4 + kq) ^ (rb & 7)) * 8);
        }
    }

    float4_t acc[8][4] = {};

    // prologue: stage K-tile 0 into buffer 0
#pragma unroll
    for (int q = 0; q < 4; ++q) {
        gload_lds16(agp[q], As + lslot[q]);
        gload_lds16(bgp[q], Bs + lslot[q]);
    }

    int cur = 0;
#pragma unroll
    for (int kt = 0; kt < 8; ++kt) {
        // my stage(kt) loads were issued a full compute-phase ago -> near-free drain
        asm volatile("s_waitcnt vmcnt(0)" ::: "memory");
        __builtin_amdgcn_s_barrier();            // publish stage(kt); gates buffer overwrite
        __builtin_amdgcn_sched_barrier(0);
        if (kt < 7) {                            // issue stage(kt+1); in flight during compute
            const int ko = (kt + 1) * 64;
            const int nb = (cur ^ 1) * 16384;
#pragma unroll
            for (int q = 0; q < 4; ++q) {
                gload_lds16(agp[q] + ko, As + nb + lslot[q]);
                gload_lds16(bgp[q] + ko, Bs + nb + lslot[q]);
            }
        }
        const unsigned short* Ab = As + cur * 16384;
        const unsigned short* Bb = Bs + cur * 16384;
#pragma unroll
        for (int ks = 0; ks < 2; ++ks) {
            short8 bfr[4];
#pragma unroll
            for (int j = 0; j < 4; ++j) bfr[j] = *(const short8*)(Bb + b_off[ks][j]);
#pragma unroll
            for (int i = 0; i < 8; ++i) {
                short8 af = *(const short8*)(Ab + a_off[ks][i]);
#pragma unroll
                for (int j = 0; j < 4; ++j)
                    acc[i][j] = __builtin_amdgcn_mfma_f32_16x16x32_bf16(af, bfr[j], acc[i][j], 0, 0, 0);
            }
        }
        cur ^= 1;
    }

    // epilogue: bias add, bf16 store, per-row partial sum of exp -> atomicAdd rowsum
    float bj[4];
#pragma unroll
    for (int j = 0; j < 4; ++j) bj[j] = bias[n_blk + n0 + j * 16 + l15];

#pragma unroll
    for (int i = 0; i < 8; ++i) {
        float se[4] = {0.f, 0.f, 0.f, 0.f};
        int grow0 = m_blk + m0 + i * 16 + kq * 4;      // + r
#pragma unroll
        for (int j = 0; j < 4; ++j) {
            int col = n_blk + n0 + j * 16 + l15;
#pragma unroll
            for (int r = 0; r < 4; ++r) {
                float v = acc[i][j][r] + bj[j];
                se[r] += __expf(v);
                if (grow0 + r < Mdim)
                    logitsbf[(size_t)(grow0 + r) * Vdim + col] = f2bf(v);
            }
        }
#pragma unroll
        for (int r = 0; r < 4; ++r) {
#pragma unroll
            for (int off = 8; off; off >>= 1)
                se[r] += __shfl_xor(se[r], off, 64);   // reduce over the 16 cols (l15)
        }
        if (l15 == 0) {
#pragma unroll
            for (int r = 0; r < 4; ++r)
                if (grow0 + r < Mdim) atomicAdd(&rowsum[grow0 + r], se[r]);
        }
    }
}

// ---------------- combine: sparse copy-dist scatter + log blend (single logits pass) ----
__global__ __launch_bounds__(512) void combine_kernel(const unsigned short* __restrict__ logitsbf,
                                                      const float* __restrict__ weights,
                                                      const float* __restrict__ p_trans,
                                                      const float* __restrict__ trans_probs,
                                                      const float* __restrict__ probs,
                                                      const int* __restrict__ idxes,
                                                      const float* __restrict__ rowsum,
                                                      float* __restrict__ out) {
    __shared__ __align__(16) float ts[VHALF];

    int bt = blockIdx.x;           // 0..799
    int b  = bt / Tdim;
    int tid = threadIdx.x;

    float pt = p_trans[bt];
    float c1 = (1.f - pt) / rowsum[bt];

    const short8* lrow8 = (const short8*)(logitsbf + (size_t)bt * Vdim);
    float4* out4 = (float4*)(out + (size_t)bt * Vdim);
    float4* ts4  = (float4*)ts;

    for (int h = 0; h < 2; ++h) {
        float4 z = make_float4(0.f, 0.f, 0.f, 0.f);
        for (int i = tid; i < VHALF / 4; i += 512) ts4[i] = z;
        __syncthreads();

        for (int i = tid; i < Sdim * Kk; i += 512) {
            float pv  = probs[b * (Sdim * Kk) + i];
            float tpv = trans_probs[b * (Sdim * Kk) + i];
            int   idx = idxes[b * (Sdim * Kk) + i];
            int   rel = idx - h * VHALF;
            if (pv > 0.05f && (unsigned)rel < (unsigned)VHALF) {
                float w = weights[bt * Sdim + (i >> 3)];
                atomicAdd(&ts[rel], w * tpv);
            }
        }
        __syncthreads();

        for (int i = tid; i < VHALF / 8; i += 512) {
            short8 x8 = lrow8[h * (VHALF / 8) + i];
            float4 t0 = ts4[i * 2];
            float4 t1 = ts4[i * 2 + 1];
            float4 o0, o1;
            o0.x = __logf(pt * t0.x + c1 * __expf(bf2f((unsigned short)x8[0])));
            o0.y = __logf(pt * t0.y + c1 * __expf(bf2f((unsigned short)x8[1])));
            o0.z = __logf(pt * t0.z + c1 * __expf(bf2f((unsigned short)x8[2])));
            o0.w = __logf(pt * t0.w + c1 * __expf(bf2f((unsigned short)x8[3])));
            o1.x = __logf(pt * t1.x + c1 * __expf(bf2f((unsigned short)x8[4])));
            o1.y = __logf(pt * t1.y + c1 * __expf(bf2f((unsigned short)x8[5])));
            o1.z = __logf(pt * t1.z + c1 * __expf(bf2f((unsigned short)x8[6])));
            o1.w = __logf(pt * t1.w + c1 * __expf(bf2f((unsigned short)x8[7])));
            out4[(h * (VHALF / 8) + i) * 2]     = o0;
            out4[(h * (VHALF / 8) + i) * 2 + 1] = o1;
        }
        __syncthreads();
    }
}

extern "C" void kernel_launch(void* const* d_in, const int* in_sizes, int n_in,
                              void* d_out, int out_size, void* d_ws, size_t ws_size,
                              hipStream_t stream) {
    const float* dec_out     = (const float*)d_in[0];   // (8,100,512)
    const float* W           = (const float*)d_in[1];   // (512,32000)
    const float* bias        = (const float*)d_in[2];   // (32000,)
    const float* weights     = (const float*)d_in[3];   // (8,100,400)
    const float* p_trans     = (const float*)d_in[4];   // (8,100,1)
    const float* trans_probs = (const float*)d_in[5];   // (8,400,8)
    const float* probs       = (const float*)d_in[6];   // (8,400,8)
    const int*   idxes       = (const int*)d_in[7];     // (8,400,8)
    float* out = (float*)d_out;

    char* wsb = (char*)d_ws;
    unsigned short* Abf      = (unsigned short*)wsb;                      // 819,200 B
    unsigned short* WT       = (unsigned short*)(wsb + (1ull << 20));     // 32.8 MB
    unsigned short* logitsbf = (unsigned short*)(wsb + (35ull << 20));    // 51.2 MB
    float*          rowsum   = (float*)(wsb + (90ull << 20));             // 3200 B

    convert_a_kernel<<<dim3((Mdim * Hdim / 4 + 255) / 256), dim3(256), 0, stream>>>(dec_out, Abf, rowsum, Mdim * Hdim / 4);
    transpose_kernel<<<dim3(Vdim / 64, Hdim / 64), dim3(256), 0, stream>>>(W, WT);
    gemm_kernel<<<dim3(500), dim3(512), 0, stream>>>(Abf, WT, bias, logitsbf, rowsum);
    combine_kernel<<<dim3(Mdim), dim3(512), 0, stream>>>(logitsbf, weights, p_trans, trans_probs,
                                                         probs, idxes, rowsum, out);
}

// Round 5
// 286.807 us; speedup vs baseline: 1.1442x; 1.0543x over previous
//
#include <hip/hip_runtime.h>

#define Bdim 8
#define Tdim 100
#define Sdim 400
#define Kk   8
#define Hdim 512
#define Vdim 32000
#define Mdim 800          // B*T
#define VCHUNK 4000       // vocab slice per combine block

typedef __attribute__((ext_vector_type(8))) short short8;     // 8 bf16 = 4 VGPRs
typedef __attribute__((ext_vector_type(4))) short short4v;    // 4 bf16 = 2 VGPRs
typedef __attribute__((ext_vector_type(4))) float float4_t;   // MFMA acc

static __device__ __forceinline__ unsigned short f2bf(float f) {
    unsigned int x = __float_as_uint(f);
    return (unsigned short)((x + 0x7fffu + ((x >> 16) & 1u)) >> 16);   // RNE
}
static __device__ __forceinline__ float bf2f(unsigned short h) {
    return __uint_as_float(((unsigned int)h) << 16);
}

// async 16B global->LDS (wave-uniform LDS base + lane*16)
static __device__ __forceinline__ void gload_lds16(const void* g, void* s) {
    __builtin_amdgcn_global_load_lds((const __attribute__((address_space(1))) void*)g,
                                     (__attribute__((address_space(3))) void*)s, 16, 0, 0);
}

// ---------------- prep: dec_out fp32 -> bf16 (vectorized x4); also zeros rowsum ----------------
__global__ void convert_a_kernel(const float* __restrict__ A, unsigned short* __restrict__ Abf,
                                 float* __restrict__ rowsum, int n4) {
    int i = blockIdx.x * blockDim.x + threadIdx.x;
    if (i < Mdim) rowsum[i] = 0.f;
    if (i < n4) {
        float4 f = ((const float4*)A)[i];
        short4v s;
        s[0] = (short)f2bf(f.x); s[1] = (short)f2bf(f.y);
        s[2] = (short)f2bf(f.z); s[3] = (short)f2bf(f.w);
        *(short4v*)(Abf + i * 4) = s;
    }
}

// ---------------- prep: W (512 x 32000) fp32 -> WT (32000 x 512) bf16 ----------------
__global__ __launch_bounds__(256) void transpose_kernel(const float* __restrict__ W,
                                                        unsigned short* __restrict__ WT) {
    __shared__ float tile[64][65];
    const int k0 = blockIdx.y * 64;
    const int v0 = blockIdx.x * 64;
    const int t  = threadIdx.x;
    const int tx = t & 15;            // float4 col within tile row
    const int ty = t >> 4;            // 0..15
#pragma unroll
    for (int i = 0; i < 64; i += 16) {
        float4 f = *(const float4*)&W[(size_t)(k0 + ty + i) * Vdim + v0 + tx * 4];
        tile[ty + i][tx * 4 + 0] = f.x;
        tile[ty + i][tx * 4 + 1] = f.y;
        tile[ty + i][tx * 4 + 2] = f.z;
        tile[ty + i][tx * 4 + 3] = f.w;
    }
    __syncthreads();
    const int c = t & 7;              // k-chunk of 8
    const int v = t >> 3;             // 0..31
#pragma unroll
    for (int i = 0; i < 64; i += 32) {
        short8 s;
#pragma unroll
        for (int j = 0; j < 8; ++j) s[j] = (short)f2bf(tile[c * 8 + j][v + i]);
        *(short8*)&WT[(size_t)(v0 + v + i) * Hdim + k0 + c * 8] = s;
    }
}

// ---------------- GEMM: logits(800x32000) = Abf * WT^T + bias; bf16 store + row sumexp ----
// Round-5: R2 geometry (best measured: 128x128, 4 waves, 64KB dbuf LDS, 2 blocks/CU,
// 1750 blocks + bijective XCD swizzle) + R4's verified sync scheme:
//   stale-vmcnt(0) wait (loads issued a full compute-phase ago -> near-free)
//   -> single s_barrier (publishes stage(kt), gates overwrite of buf(kt-1))
//   -> issue stage(kt+1)  (flies during compute)
//   -> compute(kt).
// One barrier per K-step (R2 had two + a fresh full drain).
__global__ __launch_bounds__(256) void gemm_kernel(const unsigned short* __restrict__ Abf,
                                                   const unsigned short* __restrict__ WT,
                                                   const float* __restrict__ bias,
                                                   unsigned short* __restrict__ logitsbf,
                                                   float* __restrict__ rowsum) {
    __shared__ __align__(16) unsigned short As[2 * 128 * 64];   // 2 x 16 KB
    __shared__ __align__(16) unsigned short Bs[2 * 128 * 64];   // 2 x 16 KB

    const int tid  = threadIdx.x;
    const int lane = tid & 63;
    const int wave = tid >> 6;
    const int l15  = lane & 15;
    const int kq   = lane >> 4;            // 0..3

    // bijective XCD swizzle (m204): nwg = 7*250 = 1750
    const int NWG = 7 * 250;
    const int orig = blockIdx.x;
    const int xcd = orig & 7;
    const int q8  = NWG >> 3;              // 218
    const int r8  = NWG & 7;               // 6
    const int wg  = (xcd < r8 ? xcd * (q8 + 1) : r8 * (q8 + 1) + (xcd - r8) * q8) + (orig >> 3);
    const int m_blk = (wg % 7) * 128;      // m-fastest: B-panel reuse is L2-local
    const int n_blk = (wg / 7) * 128;

    const int wm = wave & 1, wn = wave >> 1;
    const int m0 = wm * 64, n0 = wn * 64;

    // staging: 1024 16B-chunks per matrix; chunk = (q*4+wave)*64 + lane
    const unsigned short* agp[4];
    const unsigned short* bgp[4];
    int lslot[4];
#pragma unroll
    for (int q = 0; q < 4; ++q) {
        int chunk = (q * 4 + wave) * 64 + lane;
        int row = chunk >> 3, c = chunk & 7;
        int gc  = c ^ (row & 7);                 // XOR swizzle: lane fetches the chunk that
        int arow = m_blk + row;                  // belongs at its contiguous LDS slot
        if (arow >= Mdim) arow = Mdim - 1;       // clamp; epilogue masks
        agp[q] = Abf + (size_t)arow * Hdim + gc * 8;
        bgp[q] = WT + (size_t)(n_blk + row) * Hdim + gc * 8;
        lslot[q] = (q * 4 + wave) * 512;         // wave-uniform base (shorts)
    }

    // fragment LDS offsets (shorts): row*64 + ((ks*4+kq)^(row&7))*8
    int a_off[2][4], b_off[2][4];
#pragma unroll
    for (int ks = 0; ks < 2; ++ks)
#pragma unroll
        for (int i = 0; i < 4; ++i) {
            int ra = m0 + i * 16 + l15;
            a_off[ks][i] = ra * 64 + (((ks * 4 + kq) ^ (ra & 7)) * 8);
            int rb = n0 + i * 16 + l15;
            b_off[ks][i] = rb * 64 + (((ks * 4 + kq) ^ (rb & 7)) * 8);
        }

    float4_t acc[4][4] = {};

    // prologue: stage K-tile 0 into buffer 0
#pragma unroll
    for (int q = 0; q < 4; ++q) {
        gload_lds16(agp[q], As + lslot[q]);
        gload_lds16(bgp[q], Bs + lslot[q]);
    }

    int cur = 0;
#pragma unroll
    for (int kt = 0; kt < 8; ++kt) {
        // my stage(kt) loads were issued a full compute-phase ago -> near-free drain
        asm volatile("s_waitcnt vmcnt(0)" ::: "memory");
        __builtin_amdgcn_s_barrier();            // publish stage(kt); gates buffer overwrite
        __builtin_amdgcn_sched_barrier(0);
        if (kt < 7) {                            // issue stage(kt+1); in flight during compute
            const int ko = (kt + 1) * 64;
            const int nb = (cur ^ 1) * 8192;
#pragma unroll
            for (int q = 0; q < 4; ++q) {
                gload_lds16(agp[q] + ko, As + nb + lslot[q]);
                gload_lds16(bgp[q] + ko, Bs + nb + lslot[q]);
            }
        }
        const unsigned short* Ab = As + cur * 8192;
        const unsigned short* Bb = Bs + cur * 8192;
#pragma unroll
        for (int ks = 0; ks < 2; ++ks) {
            short8 af[4], bfr[4];
#pragma unroll
            for (int i = 0; i < 4; ++i) af[i]  = *(const short8*)(Ab + a_off[ks][i]);
#pragma unroll
            for (int j = 0; j < 4; ++j) bfr[j] = *(const short8*)(Bb + b_off[ks][j]);
#pragma unroll
            for (int i = 0; i < 4; ++i)
#pragma unroll
                for (int j = 0; j < 4; ++j)
                    acc[i][j] = __builtin_amdgcn_mfma_f32_16x16x32_bf16(af[i], bfr[j], acc[i][j], 0, 0, 0);
        }
        cur ^= 1;
    }

    // epilogue: bias add, bf16 store, per-row partial sum of exp -> atomicAdd rowsum
    float bj[4];
#pragma unroll
    for (int j = 0; j < 4; ++j) bj[j] = bias[n_blk + n0 + j * 16 + l15];

#pragma unroll
    for (int i = 0; i < 4; ++i) {
        float se[4] = {0.f, 0.f, 0.f, 0.f};
        int grow0 = m_blk + m0 + i * 16 + kq * 4;      // + r
#pragma unroll
        for (int j = 0; j < 4; ++j) {
            int col = n_blk + n0 + j * 16 + l15;
#pragma unroll
            for (int r = 0; r < 4; ++r) {
                float v = acc[i][j][r] + bj[j];
                se[r] += __expf(v);
                if (grow0 + r < Mdim)
                    logitsbf[(size_t)(grow0 + r) * Vdim + col] = f2bf(v);
            }
        }
#pragma unroll
        for (int r = 0; r < 4; ++r) {
#pragma unroll
            for (int off = 8; off; off >>= 1)
                se[r] += __shfl_xor(se[r], off, 64);   // reduce over the 16 cols (l15)
        }
        if (l15 == 0) {
#pragma unroll
            for (int r = 0; r < 4; ++r)
                if (grow0 + r < Mdim) atomicAdd(&rowsum[grow0 + r], se[r]);
        }
    }
}

// ---------------- combine: sparse copy-dist scatter + log blend ----------------
// Round-5 restructure: 2D grid (bt, vocab-chunk of 4000). 16 KB LDS (was 64), single
// pass (was 2 halves), 2 barriers/block (was 6), ~8 blocks/CU TLP. Scatter input
// (3200 entries/b) read once per chunk -- tiny, L2-resident.
__global__ __launch_bounds__(256) void combine_kernel(const unsigned short* __restrict__ logitsbf,
                                                      const float* __restrict__ weights,
                                                      const float* __restrict__ p_trans,
                                                      const float* __restrict__ trans_probs,
                                                      const float* __restrict__ probs,
                                                      const int* __restrict__ idxes,
                                                      const float* __restrict__ rowsum,
                                                      float* __restrict__ out) {
    __shared__ __align__(16) float ts[VCHUNK];

    const int bt  = blockIdx.x;          // 0..799
    const int c   = blockIdx.y;          // 0..7
    const int b   = bt / Tdim;
    const int tid = threadIdx.x;
    const int v0  = c * VCHUNK;

    const float pt = p_trans[bt];
    const float c1 = (1.f - pt) / rowsum[bt];

    float4* ts4 = (float4*)ts;
    const float4 z = make_float4(0.f, 0.f, 0.f, 0.f);
#pragma unroll
    for (int i = tid; i < VCHUNK / 4; i += 256) ts4[i] = z;
    __syncthreads();

    for (int i = tid; i < Sdim * Kk; i += 256) {
        float pv  = probs[b * (Sdim * Kk) + i];
        float tpv = trans_probs[b * (Sdim * Kk) + i];
        int   idx = idxes[b * (Sdim * Kk) + i];
        int   rel = idx - v0;
        if (pv > 0.05f && (unsigned)rel < (unsigned)VCHUNK) {
            float w = weights[bt * Sdim + (i >> 3)];
            atomicAdd(&ts[rel], w * tpv);
        }
    }
    __syncthreads();

    const short8* lrow8 = (const short8*)(logitsbf + (size_t)bt * Vdim + v0);
    float4* out4 = (float4*)(out + (size_t)bt * Vdim + v0);
#pragma unroll
    for (int i = tid; i < VCHUNK / 8; i += 256) {
        short8 x8 = lrow8[i];
        float4 t0 = ts4[i * 2];
        float4 t1 = ts4[i * 2 + 1];
        float4 o0, o1;
        o0.x = __logf(pt * t0.x + c1 * __expf(bf2f((unsigned short)x8[0])));
        o0.y = __logf(pt * t0.y + c1 * __expf(bf2f((unsigned short)x8[1])));
        o0.z = __logf(pt * t0.z + c1 * __expf(bf2f((unsigned short)x8[2])));
        o0.w = __logf(pt * t0.w + c1 * __expf(bf2f((unsigned short)x8[3])));
        o1.x = __logf(pt * t1.x + c1 * __expf(bf2f((unsigned short)x8[4])));
        o1.y = __logf(pt * t1.y + c1 * __expf(bf2f((unsigned short)x8[5])));
        o1.z = __logf(pt * t1.z + c1 * __expf(bf2f((unsigned short)x8[6])));
        o1.w = __logf(pt * t1.w + c1 * __expf(bf2f((unsigned short)x8[7])));
        out4[i * 2]     = o0;
        out4[i * 2 + 1] = o1;
    }
}

extern "C" void kernel_launch(void* const* d_in, const int* in_sizes, int n_in,
                              void* d_out, int out_size, void* d_ws, size_t ws_size,
                              hipStream_t stream) {
    const float* dec_out     = (const float*)d_in[0];   // (8,100,512)
    const float* W           = (const float*)d_in[1];   // (512,32000)
    const float* bias        = (const float*)d_in[2];   // (32000,)
    const float* weights     = (const float*)d_in[3];   // (8,100,400)
    const float* p_trans     = (const float*)d_in[4];   // (8,100,1)
    const float* trans_probs = (const float*)d_in[5];   // (8,400,8)
    const float* probs       = (const float*)d_in[6];   // (8,400,8)
    const int*   idxes       = (const int*)d_in[7];     // (8,400,8)
    float* out = (float*)d_out;

    char* wsb = (char*)d_ws;
    unsigned short* Abf      = (unsigned short*)wsb;                      // 819,200 B
    unsigned short* WT       = (unsigned short*)(wsb + (1ull << 20));     // 32.8 MB
    unsigned short* logitsbf = (unsigned short*)(wsb + (35ull << 20));    // 51.2 MB
    float*          rowsum   = (float*)(wsb + (90ull << 20));             // 3200 B

    convert_a_kernel<<<dim3((Mdim * Hdim / 4 + 255) / 256), dim3(256), 0, stream>>>(dec_out, Abf, rowsum, Mdim * Hdim / 4);
    transpose_kernel<<<dim3(Vdim / 64, Hdim / 64), dim3(256), 0, stream>>>(W, WT);
    gemm_kernel<<<dim3(7 * 250), dim3(256), 0, stream>>>(Abf, WT, bias, logitsbf, rowsum);
    combine_kernel<<<dim3(Mdim, Vdim / VCHUNK), dim3(256), 0, stream>>>(logitsbf, weights, p_trans, trans_probs,
                                                                        probs, idxes, rowsum, out);
}